// Round 6
// baseline (217.477 us; speedup 1.0000x reference)
//
#include <hip/hip_runtime.h>
#include <hip/hip_bf16.h>
#include <stdint.h>

#define N_TOK 8192
#define DIM   512
#define HID   2048
#define OUTD  512
#define NEXP  8

typedef short  bf16x8 __attribute__((ext_vector_type(8)));
typedef float  f32x4  __attribute__((ext_vector_type(4)));
typedef unsigned short u16x8 __attribute__((ext_vector_type(8)));
typedef unsigned short u16x4 __attribute__((ext_vector_type(4)));

// ---- workspace layout (bytes) ----
#define WS_CNT    0        // 8 ints: per-expert token counters (atomic)
#define WS_LIST   4096     // 8*8192 ints: per-expert token id lists
#define WS_XBF    266240   // 8192*512 bf16 (x converted)
#define WS_W1T    8654848  // 8*2048*512 bf16 (W1 transposed: [e][h][d])
#define WS_W2T    25432064 // 8*512*2048 bf16 (W2 transposed: [e][o][h])
#define WS_H      42209280 // 8192*2048 bf16 (hidden, expert-compacted rows)

__device__ __forceinline__ unsigned short f2bf(float f) {
    uint32_t u = __builtin_bit_cast(uint32_t, f);
    u = (u + 0x7fffu + ((u >> 16) & 1u)) >> 16;   // RNE
    return (unsigned short)u;
}

#define MFMA_BF16 __builtin_amdgcn_mfma_f32_16x16x32_bf16

// ======== fused prep: router (32) | convert_x (2048) | W1^T (8192) | W2^T (8192) ========
__global__ __launch_bounds__(256) void prep_kernel(
    const float* __restrict__ x, const float* __restrict__ wr, const float* __restrict__ br,
    const float* __restrict__ w1, const float* __restrict__ w2,
    float* __restrict__ probs, int* __restrict__ cnt, int* __restrict__ list,
    unsigned short* __restrict__ xbf, unsigned short* __restrict__ w1t, unsigned short* __restrict__ w2t)
{
    const int bid = blockIdx.x, tid = threadIdx.x;
    if (bid < 32) {
        // ---- router: fp32 logits -> softmax -> probs, argmax -> expert lists ----
        __shared__ int lcnt[NEXP];
        __shared__ int lbase[NEXP];
        if (tid < NEXP) lcnt[tid] = 0;
        __syncthreads();
        const int n = bid * 256 + tid;
        float acc[NEXP];
        #pragma unroll
        for (int e = 0; e < NEXP; e++) acc[e] = br[e];
        const f32x4* xr = (const f32x4*)(x + (size_t)n * DIM);
        for (int i = 0; i < DIM / 4; i++) {
            f32x4 v = xr[i];
            #pragma unroll
            for (int d = 0; d < 4; d++) {
                const float xv = v[d];
                #pragma unroll
                for (int e = 0; e < NEXP; e++)
                    acc[e] += xv * wr[(i * 4 + d) * NEXP + e];
            }
        }
        float mx = acc[0]; int am = 0;
        #pragma unroll
        for (int e = 1; e < NEXP; e++) if (acc[e] > mx) { mx = acc[e]; am = e; }
        float p[NEXP]; float s = 0.f;
        #pragma unroll
        for (int e = 0; e < NEXP; e++) { p[e] = expf(acc[e] - mx); s += p[e]; }
        const float inv = 1.f / s;
        f32x4 p0, p1;
        #pragma unroll
        for (int e = 0; e < 4; e++) { p0[e] = p[e] * inv; p1[e] = p[e + 4] * inv; }
        *(f32x4*)&probs[(size_t)n * NEXP]     = p0;
        *(f32x4*)&probs[(size_t)n * NEXP + 4] = p1;
        const int slot = atomicAdd(&lcnt[am], 1);
        __syncthreads();
        if (tid < NEXP) lbase[tid] = atomicAdd(&cnt[tid], lcnt[tid]);
        __syncthreads();
        list[am * N_TOK + lbase[am] + slot] = n;
    } else if (bid < 2080) {
        // ---- convert x -> bf16, 8 elems/thread ----
        const size_t i = (size_t)(bid - 32) * 256 + tid;
        f32x4 a = *(const f32x4*)&x[i * 8];
        f32x4 b = *(const f32x4*)&x[i * 8 + 4];
        u16x8 o;
        #pragma unroll
        for (int j = 0; j < 4; j++) { o[j] = f2bf(a[j]); o[4 + j] = f2bf(b[j]); }
        *(u16x8*)&xbf[i * 8] = o;
    } else {
        // ---- weight transpose to bf16 [e][n][k] ----
        __shared__ float t[32][33];
        const float* pin; unsigned short* pout; int R, C, r0, c0;
        if (bid < 10272) {
            const int loc = bid - 2080, e = loc >> 10, l2 = loc & 1023;
            pin = w1 + (size_t)e * DIM * HID; pout = w1t + (size_t)e * DIM * HID;
            R = DIM; C = HID; r0 = (l2 >> 6) * 32; c0 = (l2 & 63) * 32;
        } else {
            const int loc = bid - 10272, e = loc >> 10, l2 = loc & 1023;
            pin = w2 + (size_t)e * HID * OUTD; pout = w2t + (size_t)e * HID * OUTD;
            R = HID; C = OUTD; r0 = (l2 >> 4) * 32; c0 = (l2 & 15) * 32;
        }
        const int lr = tid >> 3, lc4 = (tid & 7) * 4;
        f32x4 v = *(const f32x4*)&pin[(size_t)(r0 + lr) * C + c0 + lc4];
        #pragma unroll
        for (int i = 0; i < 4; i++) t[lr][lc4 + i] = v[i];
        __syncthreads();
        u16x4 o;
        #pragma unroll
        for (int i = 0; i < 4; i++) o[i] = f2bf(t[lc4 + i][lr]);
        *(u16x4*)&pout[(size_t)(c0 + lr) * R + r0 + lc4] = o;
    }
}

// bijective per-XCD chunk swizzle: phys bid -> virtual id in [0,nwg)
__device__ __forceinline__ int xcd_swizzle(int bid, int nwg, bool& valid) {
    const int xcd = bid & 7, cidx = bid >> 3;
    const int q = nwg >> 3, r = nwg & 7;
    const int csz = q + (xcd < r ? 1 : 0);
    valid = (cidx < csz);
    return (xcd < r ? xcd * (q + 1) : r * (q + 1) + (xcd - r) * q) + cidx;
}

// tile -> (expert, row0, base) from cnt[8]; 64-row tiles
__device__ __forceinline__ void tile_map64(const int* __restrict__ cnt, int tile,
                                           int& e, int& row0, int& bs, int& m_e, int& ntiles) {
    int c[NEXP]; ntiles = 0;
    #pragma unroll
    for (int i = 0; i < NEXP; i++) { c[i] = cnt[i]; ntiles += (c[i] + 63) >> 6; }
    int t = tile, b = 0, ei = 0;
    #pragma unroll
    for (int i = 0; i < NEXP; i++) {
        const int nt = (c[i] + 63) >> 6;
        if (t >= 0 && t < nt) { ei = i; row0 = t << 6; bs = b; m_e = c[i]; }
        t -= nt; b += c[i];
    }
    e = ei;
}

// ======== GEMM engine: 1 wave per block, 64x64 output tile, NO LDS, reg ring-3 ========
// Fragments loaded global->VGPR directly (1 dwordx4/frag); compiler counts vmcnt per reg.

// ---- GEMM1: h[slot,:] = relu(x[tok] @ W1[e] + b1[e]); K=512 -> 16 k-chunks ----
__global__ __launch_bounds__(64, 2) void gemm1_kernel(
    const unsigned short* __restrict__ xbf, const unsigned short* __restrict__ w1t,
    const float* __restrict__ b1, const int* __restrict__ list,
    const int* __restrict__ cnt, unsigned short* __restrict__ h)
{
    int e = 0, row0 = 0, bs = 0, m_e = 0, ntm = 0;
    tile_map64(cnt, 0, e, row0, bs, m_e, ntm);
    const int nwg = ntm * 32;                       // 32 n-tiles (HID/64), ntile fastest
    bool valid; const int v = xcd_swizzle(blockIdx.x, nwg, valid);
    if (!valid) return;
    const int mt = v >> 5, nt = v & 31;
    tile_map64(cnt, mt, e, row0, bs, m_e, ntm);
    const int n0 = nt * 64;

    const int lane = threadIdx.x;
    const int lrow = lane & 15, gk = lane >> 4;     // frag row sel / k-group

    const unsigned short* aP[4]; const unsigned short* bP[4];
    #pragma unroll
    for (int f = 0; f < 4; f++) {
        int r = row0 + f * 16 + lrow; if (r >= m_e) r = m_e - 1;
        const int tok = list[e * N_TOK + r];
        aP[f] = xbf + (size_t)tok * DIM + gk * 8;
        bP[f] = w1t + ((size_t)e * HID + n0 + f * 16 + lrow) * DIM + gk * 8;
    }

    f32x4 acc[4][4] = {};
    bf16x8 aR[3][4], bR[3][4];                      // ring-3 staging in VGPRs

    #pragma unroll
    for (int s = 0; s < 2; s++)
        #pragma unroll
        for (int f = 0; f < 4; f++) {
            aR[s][f] = *(const bf16x8*)(aP[f] + s * 32);
            bR[s][f] = *(const bf16x8*)(bP[f] + s * 32);
        }

    #pragma unroll
    for (int t = 0; t < 16; t++) {                  // k = t*32
        const int s = t % 3;
        if (t + 2 < 16) {
            const int sn = (t + 2) % 3;
            #pragma unroll
            for (int f = 0; f < 4; f++) {
                aR[sn][f] = *(const bf16x8*)(aP[f] + (t + 2) * 32);
                bR[sn][f] = *(const bf16x8*)(bP[f] + (t + 2) * 32);
            }
        }
        #pragma unroll
        for (int mf = 0; mf < 4; mf++)
            #pragma unroll
            for (int nf = 0; nf < 4; nf++)
                acc[mf][nf] = MFMA_BF16(aR[s][mf], bR[s][nf], acc[mf][nf], 0, 0, 0);
    }

    const int hbase = bs + row0;
    float bias[4];
    #pragma unroll
    for (int nf = 0; nf < 4; nf++) bias[nf] = b1[e * HID + n0 + nf * 16 + lrow];
    #pragma unroll
    for (int mf = 0; mf < 4; mf++) {
        #pragma unroll
        for (int j = 0; j < 4; j++) {
            const int m = mf * 16 + gk * 4 + j;
            if (row0 + m < m_e) {
                const size_t ro = (size_t)(hbase + m) * HID + n0;
                #pragma unroll
                for (int nf = 0; nf < 4; nf++) {
                    float vv = acc[mf][nf][j] + bias[nf];
                    h[ro + nf * 16 + lrow] = f2bf(vv > 0.f ? vv : 0.f);
                }
            }
        }
    }
}

// ---- GEMM2: out[tok,:] = h[slot] @ W2[e] + b2[e]; K=2048 -> 64 k-chunks ----
__global__ __launch_bounds__(64, 2) void gemm2_kernel(
    const unsigned short* __restrict__ h, const unsigned short* __restrict__ w2t,
    const float* __restrict__ b2, const int* __restrict__ list,
    const int* __restrict__ cnt, float* __restrict__ out, float* __restrict__ counts)
{
    if (blockIdx.x == 0 && threadIdx.x < NEXP) counts[threadIdx.x] = (float)cnt[threadIdx.x];

    int e = 0, row0 = 0, bs = 0, m_e = 0, ntm = 0;
    tile_map64(cnt, 0, e, row0, bs, m_e, ntm);
    const int nwg = ntm * 8;                        // 8 n-tiles (OUTD/64), ntile fastest
    bool valid; const int v = xcd_swizzle(blockIdx.x, nwg, valid);
    if (!valid) return;
    const int mt = v >> 3, nt = v & 7;
    tile_map64(cnt, mt, e, row0, bs, m_e, ntm);
    const int n0 = nt * 64;

    const int lane = threadIdx.x;
    const int lrow = lane & 15, gk = lane >> 4;

    const unsigned short* aP[4]; const unsigned short* bP[4];
    #pragma unroll
    for (int f = 0; f < 4; f++) {
        int r = row0 + f * 16 + lrow; if (r >= m_e) r = m_e - 1;
        aP[f] = h + (size_t)(bs + r) * HID + gk * 8;           // compact rows
        bP[f] = w2t + ((size_t)e * OUTD + n0 + f * 16 + lrow) * HID + gk * 8;
    }

    f32x4 acc[4][4] = {};
    bf16x8 aR[3][4], bR[3][4];

    #pragma unroll
    for (int s = 0; s < 2; s++)
        #pragma unroll
        for (int f = 0; f < 4; f++) {
            aR[s][f] = *(const bf16x8*)(aP[f] + s * 32);
            bR[s][f] = *(const bf16x8*)(bP[f] + s * 32);
        }

    #pragma unroll
    for (int t = 0; t < 64; t++) {                  // k = t*32
        const int s = t % 3;
        if (t + 2 < 64) {
            const int sn = (t + 2) % 3;
            #pragma unroll
            for (int f = 0; f < 4; f++) {
                aR[sn][f] = *(const bf16x8*)(aP[f] + (t + 2) * 32);
                bR[sn][f] = *(const bf16x8*)(bP[f] + (t + 2) * 32);
            }
        }
        #pragma unroll
        for (int mf = 0; mf < 4; mf++)
            #pragma unroll
            for (int nf = 0; nf < 4; nf++)
                acc[mf][nf] = MFMA_BF16(aR[s][mf], bR[s][nf], acc[mf][nf], 0, 0, 0);
    }

    float bias[4];
    #pragma unroll
    for (int nf = 0; nf < 4; nf++) bias[nf] = b2[e * OUTD + n0 + nf * 16 + lrow];
    #pragma unroll
    for (int mf = 0; mf < 4; mf++) {
        #pragma unroll
        for (int j = 0; j < 4; j++) {
            const int m = mf * 16 + gk * 4 + j;
            const int r = row0 + m;
            if (r < m_e) {
                const int tok = list[e * N_TOK + r];
                const size_t ro = (size_t)tok * OUTD + n0;
                #pragma unroll
                for (int nf = 0; nf < 4; nf++)
                    out[ro + nf * 16 + lrow] = acc[mf][nf][j] + bias[nf];
            }
        }
    }
}

extern "C" void kernel_launch(void* const* d_in, const int* in_sizes, int n_in,
                              void* d_out, int out_size, void* d_ws, size_t ws_size,
                              hipStream_t stream) {
    (void)in_sizes; (void)n_in; (void)out_size; (void)ws_size;
    const float* x  = (const float*)d_in[0];
    const float* wr = (const float*)d_in[1];
    const float* br = (const float*)d_in[2];
    const float* w1 = (const float*)d_in[3];
    const float* b1 = (const float*)d_in[4];
    const float* w2 = (const float*)d_in[5];
    const float* b2 = (const float*)d_in[6];

    float* out    = (float*)d_out;
    float* probs  = out + (size_t)N_TOK * OUTD;
    float* counts = probs + (size_t)N_TOK * NEXP;

    char* ws = (char*)d_ws;
    int* cnt     = (int*)(ws + WS_CNT);
    int* list    = (int*)(ws + WS_LIST);
    unsigned short* xbf = (unsigned short*)(ws + WS_XBF);
    unsigned short* w1t = (unsigned short*)(ws + WS_W1T);
    unsigned short* w2t = (unsigned short*)(ws + WS_W2T);
    unsigned short* hbf = (unsigned short*)(ws + WS_H);

    hipMemsetAsync(cnt, 0, NEXP * sizeof(int), stream);
    prep_kernel<<<18464, 256, 0, stream>>>(x, wr, br, w1, w2, probs, cnt, list, xbf, w1t, w2t);
    gemm1_kernel<<<4352, 64, 0, stream>>>(xbf, w1t, b1, list, cnt, hbf);   // 136 mtiles * 32 ntiles max
    gemm2_kernel<<<1088, 64, 0, stream>>>(hbf, w2t, b2, list, cnt, out, counts); // 136 * 8 max
}

// Round 7
// 112.153 us; speedup vs baseline: 1.9391x; 1.9391x over previous
//
#include <hip/hip_runtime.h>
#include <hip/hip_bf16.h>
#include <stdint.h>

#define N_TOK 8192
#define DIM   512
#define HID   2048
#define OUTD  512
#define NEXP  8

typedef short  bf16x8 __attribute__((ext_vector_type(8)));
typedef float  f32x4  __attribute__((ext_vector_type(4)));
typedef unsigned short u16x8 __attribute__((ext_vector_type(8)));
typedef unsigned short u16x4 __attribute__((ext_vector_type(4)));

// ---- workspace layout (bytes) ----
#define WS_CNT    0        // 8 ints: per-expert token counters (atomic)
#define WS_LIST   4096     // 8*8192 ints: per-expert token id lists
#define WS_XBF    266240   // 8192*512 bf16 (x converted)
#define WS_W1T    8654848  // 8*2048*512 bf16 (W1 transposed: [e][h][d])
#define WS_W2T    25432064 // 8*512*2048 bf16 (W2 transposed: [e][o][h])
#define WS_H      42209280 // 8192*2048 bf16 (hidden, expert-compacted rows)

__device__ __forceinline__ unsigned short f2bf(float f) {
    uint32_t u = __builtin_bit_cast(uint32_t, f);
    u = (u + 0x7fffu + ((u >> 16) & 1u)) >> 16;   // RNE
    return (unsigned short)u;
}

// async global->LDS, 16B per lane; LDS dest = wave-uniform base + lane*16
__device__ __forceinline__ void gload16(const unsigned short* g, unsigned short* l) {
    __builtin_amdgcn_global_load_lds(
        (const __attribute__((address_space(1))) unsigned int*)g,
        (__attribute__((address_space(3))) unsigned int*)l, 16, 0, 0);
}

#define MFMA_BF16 __builtin_amdgcn_mfma_f32_16x16x32_bf16

// ======== fused prep: router (32) | convert_x (2048) | W1^T (8192) | W2^T (8192) ========
__global__ __launch_bounds__(256) void prep_kernel(
    const float* __restrict__ x, const float* __restrict__ wr, const float* __restrict__ br,
    const float* __restrict__ w1, const float* __restrict__ w2,
    float* __restrict__ probs, int* __restrict__ cnt, int* __restrict__ list,
    unsigned short* __restrict__ xbf, unsigned short* __restrict__ w1t, unsigned short* __restrict__ w2t)
{
    const int bid = blockIdx.x, tid = threadIdx.x;
    if (bid < 32) {
        __shared__ int lcnt[NEXP];
        __shared__ int lbase[NEXP];
        if (tid < NEXP) lcnt[tid] = 0;
        __syncthreads();
        const int n = bid * 256 + tid;
        float acc[NEXP];
        #pragma unroll
        for (int e = 0; e < NEXP; e++) acc[e] = br[e];
        const f32x4* xr = (const f32x4*)(x + (size_t)n * DIM);
        for (int i = 0; i < DIM / 4; i++) {
            f32x4 v = xr[i];
            #pragma unroll
            for (int d = 0; d < 4; d++) {
                const float xv = v[d];
                #pragma unroll
                for (int e = 0; e < NEXP; e++)
                    acc[e] += xv * wr[(i * 4 + d) * NEXP + e];
            }
        }
        float mx = acc[0]; int am = 0;
        #pragma unroll
        for (int e = 1; e < NEXP; e++) if (acc[e] > mx) { mx = acc[e]; am = e; }
        float p[NEXP]; float s = 0.f;
        #pragma unroll
        for (int e = 0; e < NEXP; e++) { p[e] = expf(acc[e] - mx); s += p[e]; }
        const float inv = 1.f / s;
        f32x4 p0, p1;
        #pragma unroll
        for (int e = 0; e < 4; e++) { p0[e] = p[e] * inv; p1[e] = p[e + 4] * inv; }
        *(f32x4*)&probs[(size_t)n * NEXP]     = p0;
        *(f32x4*)&probs[(size_t)n * NEXP + 4] = p1;
        const int slot = atomicAdd(&lcnt[am], 1);
        __syncthreads();
        if (tid < NEXP) lbase[tid] = atomicAdd(&cnt[tid], lcnt[tid]);
        __syncthreads();
        list[am * N_TOK + lbase[am] + slot] = n;
    } else if (bid < 2080) {
        const size_t i = (size_t)(bid - 32) * 256 + tid;
        f32x4 a = *(const f32x4*)&x[i * 8];
        f32x4 b = *(const f32x4*)&x[i * 8 + 4];
        u16x8 o;
        #pragma unroll
        for (int j = 0; j < 4; j++) { o[j] = f2bf(a[j]); o[4 + j] = f2bf(b[j]); }
        *(u16x8*)&xbf[i * 8] = o;
    } else {
        __shared__ float t[32][33];
        const float* pin; unsigned short* pout; int R, C, r0, c0;
        if (bid < 10272) {
            const int loc = bid - 2080, e = loc >> 10, l2 = loc & 1023;
            pin = w1 + (size_t)e * DIM * HID; pout = w1t + (size_t)e * DIM * HID;
            R = DIM; C = HID; r0 = (l2 >> 6) * 32; c0 = (l2 & 63) * 32;
        } else {
            const int loc = bid - 10272, e = loc >> 10, l2 = loc & 1023;
            pin = w2 + (size_t)e * HID * OUTD; pout = w2t + (size_t)e * HID * OUTD;
            R = HID; C = OUTD; r0 = (l2 >> 4) * 32; c0 = (l2 & 15) * 32;
        }
        const int lr = tid >> 3, lc4 = (tid & 7) * 4;
        f32x4 v = *(const f32x4*)&pin[(size_t)(r0 + lr) * C + c0 + lc4];
        #pragma unroll
        for (int i = 0; i < 4; i++) t[lr][lc4 + i] = v[i];
        __syncthreads();
        u16x4 o;
        #pragma unroll
        for (int i = 0; i < 4; i++) o[i] = f2bf(t[lc4 + i][lr]);
        *(u16x4*)&pout[(size_t)(c0 + lr) * R + r0 + lc4] = o;
    }
}

// bijective per-XCD chunk swizzle: phys bid -> virtual id in [0,nwg)
__device__ __forceinline__ int xcd_swizzle(int bid, int nwg, bool& valid) {
    const int xcd = bid & 7, cidx = bid >> 3;
    const int q = nwg >> 3, r = nwg & 7;
    const int csz = q + (xcd < r ? 1 : 0);
    valid = (cidx < csz);
    return (xcd < r ? xcd * (q + 1) : r * (q + 1) + (xcd - r) * q) + cidx;
}

// tile -> (expert, row0, base) from cnt[8]; wave-uniform scalar work. SH = log2(tile rows)
template<int SH>
__device__ __forceinline__ void tile_map(const int* __restrict__ cnt, int tile,
                                         int& e, int& row0, int& bs, int& m_e, int& ntiles) {
    const int G = 1 << SH, GM = G - 1;
    int c[NEXP]; ntiles = 0;
    #pragma unroll
    for (int i = 0; i < NEXP; i++) { c[i] = cnt[i]; ntiles += (c[i] + GM) >> SH; }
    int t = tile, b = 0, ei = 0;
    #pragma unroll
    for (int i = 0; i < NEXP; i++) {
        const int nt = (c[i] + GM) >> SH;
        if (t >= 0 && t < nt) { ei = i; row0 = t << SH; bs = b; m_e = c[i]; }
        t -= nt; b += c[i];
    }
    e = ei;
}

// ---- GEMM1: h[slot,:] = relu(x[tok] @ W1[e] + b1[e]) ----
// 128m x 256n tile, BK=64, 512 thr / 8 waves (wave-out 64x64), single-buffer 1-phase.
// LDS 49KB -> 3-resident by LDS; launch_bounds(512,4) caps VGPR at 128 -> 2 blocks/CU.
__global__ __launch_bounds__(512, 4) void gemm1_kernel(
    const unsigned short* __restrict__ xbf, const unsigned short* __restrict__ w1t,
    const float* __restrict__ b1, const int* __restrict__ list,
    const int* __restrict__ cnt, unsigned short* __restrict__ h)
{
    int e = 0, row0 = 0, bs = 0, m_e = 0, ntm = 0;
    tile_map<7>(cnt, 0, e, row0, bs, m_e, ntm);
    const int nwg = ntm * 8;                        // 8 n-tiles (HID/256)
    bool valid; const int v = xcd_swizzle(blockIdx.x, nwg, valid);
    if (!valid) return;
    const int tile = v >> 3, ntile = v & 7;
    tile_map<7>(cnt, tile, e, row0, bs, m_e, ntm);
    const int n0 = ntile * 256;

    __shared__ unsigned short ldsA[128 * 64] __attribute__((aligned(16)));  // 16KB
    __shared__ unsigned short ldsB[256 * 64] __attribute__((aligned(16)));  // 32KB
    __shared__ int ldsTok[128];
    const int tid = threadIdx.x;
    if (tid < 128) { int r = row0 + tid; if (r >= m_e) r = m_e - 1; ldsTok[tid] = list[e * N_TOK + r]; }
    __syncthreads();

    const int gslot = tid & 7;
    const unsigned short* aSrc[2]; const unsigned short* bSrc[4];
    #pragma unroll
    for (int g = 0; g < 2; g++) {
        const int row = (g * 512 + tid) >> 3;       // 0..127
        const int col = ((gslot ^ (row & 7)) << 3);
        aSrc[g] = xbf + (size_t)ldsTok[row] * DIM + col;
    }
    #pragma unroll
    for (int g = 0; g < 4; g++) {
        const int row = (g * 512 + tid) >> 3;       // 0..255
        const int col = ((gslot ^ (row & 7)) << 3);
        bSrc[g] = w1t + ((size_t)e * HID + n0 + row) * DIM + col;
    }

    f32x4 acc[4][4] = {};
    const int lane = tid & 63, wid = tid >> 6;
    const int wr = wid >> 2, wc = wid & 3;          // wave-out 64x64
    const int lrow = lane & 15, gk = lane >> 4, lm = lrow & 7;

    int rowA[4], rowB[4];
    #pragma unroll
    for (int f = 0; f < 4; f++) rowA[f] = (wr * 64 + f * 16 + lrow) * 64;
    #pragma unroll
    for (int f = 0; f < 4; f++) rowB[f] = (wc * 64 + f * 16 + lrow) * 64;

    for (int t = 0; t < 8; t++) {
        const int k0 = t * 64;
        __syncthreads();                            // prior comp done reading
        #pragma unroll
        for (int g = 0; g < 2; g++)
            gload16(aSrc[g] + k0, ldsA + ((g << 9) + (tid & 448)) * 8);
        #pragma unroll
        for (int g = 0; g < 4; g++)
            gload16(bSrc[g] + k0, ldsB + ((g << 9) + (tid & 448)) * 8);
        __syncthreads();                            // drains vmcnt(0) before barrier
        #pragma unroll
        for (int kk = 0; kk < 2; kk++) {
            bf16x8 av[4], bv[4];
            #pragma unroll
            for (int f = 0; f < 4; f++)
                av[f] = *(const bf16x8*)&ldsA[rowA[f] + ((((kk << 2) + gk) ^ lm) << 3)];
            #pragma unroll
            for (int f = 0; f < 4; f++)
                bv[f] = *(const bf16x8*)&ldsB[rowB[f] + ((((kk << 2) + gk) ^ lm) << 3)];
            #pragma unroll
            for (int mf = 0; mf < 4; mf++)
                #pragma unroll
                for (int nf = 0; nf < 4; nf++)
                    acc[mf][nf] = MFMA_BF16(av[mf], bv[nf], acc[mf][nf], 0, 0, 0);
        }
    }

    const int hbase = bs + row0;
    float bias[4];
    #pragma unroll
    for (int nf = 0; nf < 4; nf++) bias[nf] = b1[e * HID + n0 + wc * 64 + nf * 16 + lrow];
    #pragma unroll
    for (int mf = 0; mf < 4; mf++) {
        #pragma unroll
        for (int j = 0; j < 4; j++) {
            const int m = wr * 64 + mf * 16 + gk * 4 + j;
            if (row0 + m < m_e) {
                const size_t ro = (size_t)(hbase + m) * HID + n0 + wc * 64;
                #pragma unroll
                for (int nf = 0; nf < 4; nf++) {
                    float vv = acc[mf][nf][j] + bias[nf];
                    h[ro + nf * 16 + lrow] = f2bf(vv > 0.f ? vv : 0.f);
                }
            }
        }
    }
}

// ---- GEMM2: out[tok,:] = h[slot] @ W2[e] + b2[e]; 128x64, BK=64, K=2048, 256 thr, 1-phase ----
__global__ __launch_bounds__(256) void gemm2_kernel(
    const unsigned short* __restrict__ h, const unsigned short* __restrict__ w2t,
    const float* __restrict__ b2, const int* __restrict__ list,
    const int* __restrict__ cnt, float* __restrict__ out, float* __restrict__ counts)
{
    const int tid = threadIdx.x;
    if (blockIdx.x == 0 && tid < NEXP) counts[tid] = (float)cnt[tid];

    int e = 0, row0 = 0, bs = 0, m_e = 0, ntm = 0;
    tile_map<7>(cnt, 0, e, row0, bs, m_e, ntm);
    const int nwg = ntm * 8;                        // 8 n-tiles (OUTD/64)
    bool valid; const int v = xcd_swizzle(blockIdx.x, nwg, valid);
    if (!valid) return;
    const int tile = v >> 3, ntile = v & 7;
    tile_map<7>(cnt, tile, e, row0, bs, m_e, ntm);
    const int n0 = ntile * 64;

    __shared__ unsigned short ldsA[128 * 64] __attribute__((aligned(16)));  // 16KB
    __shared__ unsigned short ldsB[64 * 64]  __attribute__((aligned(16)));  // 8KB
    __shared__ int ldsTok[128];
    if (tid < 128) { int r = row0 + tid; if (r >= m_e) r = m_e - 1; ldsTok[tid] = list[e * N_TOK + r]; }
    __syncthreads();

    const int gslot = tid & 7;
    const unsigned short* aSrc[4]; const unsigned short* bSrc[2];
    #pragma unroll
    for (int i = 0; i < 4; i++) {
        const int row = (i * 256 + tid) >> 3;       // 0..127
        const int col = ((gslot ^ (row & 7)) << 3);
        int slot = row0 + row; if (slot >= m_e) slot = m_e - 1;
        aSrc[i] = h + (size_t)(bs + slot) * HID + col;
    }
    #pragma unroll
    for (int i = 0; i < 2; i++) {
        const int row = (i * 256 + tid) >> 3;       // 0..63
        const int col = ((gslot ^ (row & 7)) << 3);
        bSrc[i] = w2t + ((size_t)e * OUTD + n0 + row) * HID + col;
    }

    f32x4 acc[4][2] = {};
    const int lane = tid & 63, wid = tid >> 6;
    const int wm = (wid >> 1) * 64, wn = (wid & 1) * 32;
    const int lrow = lane & 15, gk = lane >> 4, lm = lrow & 7;

    int rowA[4], rowB[2];
    #pragma unroll
    for (int f = 0; f < 4; f++) rowA[f] = (wm + f * 16 + lrow) * 64;
    #pragma unroll
    for (int f = 0; f < 2; f++) rowB[f] = (wn + f * 16 + lrow) * 64;

    for (int t = 0; t < 32; t++) {
        const int k0 = t * 64;
        __syncthreads();
        #pragma unroll
        for (int i = 0; i < 4; i++)
            gload16(aSrc[i] + k0, ldsA + ((i << 8) + (tid & 192)) * 8);
        #pragma unroll
        for (int i = 0; i < 2; i++)
            gload16(bSrc[i] + k0, ldsB + ((i << 8) + (tid & 192)) * 8);
        __syncthreads();
        #pragma unroll
        for (int kk = 0; kk < 2; kk++) {
            bf16x8 av[4], bv[2];
            #pragma unroll
            for (int f = 0; f < 4; f++)
                av[f] = *(const bf16x8*)&ldsA[rowA[f] + ((((kk << 2) + gk) ^ lm) << 3)];
            #pragma unroll
            for (int f = 0; f < 2; f++)
                bv[f] = *(const bf16x8*)&ldsB[rowB[f] + ((((kk << 2) + gk) ^ lm) << 3)];
            #pragma unroll
            for (int mf = 0; mf < 4; mf++)
                #pragma unroll
                for (int nf = 0; nf < 2; nf++)
                    acc[mf][nf] = MFMA_BF16(av[mf], bv[nf], acc[mf][nf], 0, 0, 0);
        }
    }

    float bias[2];
    #pragma unroll
    for (int nf = 0; nf < 2; nf++) bias[nf] = b2[e * OUTD + n0 + wn + nf * 16 + lrow];
    #pragma unroll
    for (int mf = 0; mf < 4; mf++) {
        #pragma unroll
        for (int j = 0; j < 4; j++) {
            const int m = wm + mf * 16 + gk * 4 + j;
            if (row0 + m < m_e) {
                const size_t ro = (size_t)ldsTok[m] * OUTD + n0 + wn;
                #pragma unroll
                for (int nf = 0; nf < 2; nf++)
                    out[ro + nf * 16 + lrow] = acc[mf][nf][j] + bias[nf];
            }
        }
    }
}

extern "C" void kernel_launch(void* const* d_in, const int* in_sizes, int n_in,
                              void* d_out, int out_size, void* d_ws, size_t ws_size,
                              hipStream_t stream) {
    (void)in_sizes; (void)n_in; (void)out_size; (void)ws_size;
    const float* x  = (const float*)d_in[0];
    const float* wr = (const float*)d_in[1];
    const float* br = (const float*)d_in[2];
    const float* w1 = (const float*)d_in[3];
    const float* b1 = (const float*)d_in[4];
    const float* w2 = (const float*)d_in[5];
    const float* b2 = (const float*)d_in[6];

    float* out    = (float*)d_out;
    float* probs  = out + (size_t)N_TOK * OUTD;
    float* counts = probs + (size_t)N_TOK * NEXP;

    char* ws = (char*)d_ws;
    int* cnt     = (int*)(ws + WS_CNT);
    int* list    = (int*)(ws + WS_LIST);
    unsigned short* xbf = (unsigned short*)(ws + WS_XBF);
    unsigned short* w1t = (unsigned short*)(ws + WS_W1T);
    unsigned short* w2t = (unsigned short*)(ws + WS_W2T);
    unsigned short* hbf = (unsigned short*)(ws + WS_H);

    hipMemsetAsync(cnt, 0, NEXP * sizeof(int), stream);
    prep_kernel<<<18464, 256, 0, stream>>>(x, wr, br, w1, w2, probs, cnt, list, xbf, w1t, w2t);
    gemm1_kernel<<<576, 512, 0, stream>>>(xbf, w1t, b1, list, cnt, hbf);     // <=71 mtiles * 8 ntiles
    gemm2_kernel<<<576, 256, 0, stream>>>(hbf, w2t, b2, list, cnt, out, counts);
}